// Round 11
// baseline (3346.499 us; speedup 1.0000x reference)
//
#include <hip/hip_runtime.h>
#include <hip/hip_bf16.h>

#define NP 63   // number of patches

typedef __attribute__((ext_vector_type(8))) short short8;
typedef __attribute__((ext_vector_type(4))) float f32x4;
typedef __attribute__((ext_vector_type(4))) int i32x4;
typedef unsigned char uchar;

__device__ __forceinline__ float sigf(float x){ return 1.0f/(1.0f+expf(-x)); }
__device__ __forceinline__ float u2f(ushort u){ __hip_bfloat16 h; *(ushort*)&h = u; return __bfloat162float(h); }
__device__ __forceinline__ ushort f2u(float f){ __hip_bfloat16 h = __float2bfloat16(f); return *(ushort*)&h; }

// HW transcendental gate functions (scan epilogue critical path):
// v_exp_f32 = 2^x (1 ulp), v_rcp_f32 (~22-bit). Args clamped to +-126 for inf-safety.
__device__ __forceinline__ float fexp2(float x){ float r; asm("v_exp_f32 %0, %1" : "=v"(r) : "v"(x)); return r; }
__device__ __forceinline__ float frcp (float x){ float r; asm("v_rcp_f32 %0, %1" : "=v"(r) : "v"(x)); return r; }
#define LOG2E 1.442695040888963f
__device__ __forceinline__ float sig_fast(float x){
  float a = fminf(fmaxf(-LOG2E*x, -126.f), 126.f);
  return frcp(1.f + fexp2(a));
}
__device__ __forceinline__ float tanh_fast(float x){
  float a = fminf(fmaxf(-2.f*LOG2E*x, -126.f), 126.f);
  float e = fexp2(a);
  return (1.f - e) * frcp(1.f + e);
}

// ---------------- RevIN stats (+ zero persistent-scan flag bytes) ----------------
__global__ void __launch_bounds__(256) k_revin(const float* __restrict__ series,
    float* __restrict__ meanv, float* __restrict__ stdv, int* __restrict__ bar)
{
  int n = blockIdx.x, tid = threadIdx.x;
  if(n==0 && tid<64) bar[tid] = 0;   // 256 flag bytes (16 groups x 16 blocks)
  __shared__ float s1[256], s2[256];
  const float* p = series + n*512;
  float a = 0.f, b = 0.f;
  for(int t=tid;t<512;t+=256){ float v=p[t]; a+=v; b+=v*v; }
  s1[tid]=a; s2[tid]=b; __syncthreads();
  for(int s=128;s>0;s>>=1){
    if(tid<s){ s1[tid]+=s1[tid+s]; s2[tid]+=s2[tid+s]; }
    __syncthreads();
  }
  if(tid==0){
    float mu = s1[0]*(1.f/512.f);
    float var = fmaxf(s2[0]*(1.f/512.f) - mu*mu, 0.f);
    meanv[n]=mu; stdv[n]=sqrtf(var+1e-5f);
  }
}

// ---------------- patch embed -> bf16 xbuf ----------------
__global__ void __launch_bounds__(256) k_patch(const float* __restrict__ series,
    const float* __restrict__ rs, const float* __restrict__ rb,
    const float* __restrict__ up_w, const float* __restrict__ meanv,
    const float* __restrict__ stdv, ushort* __restrict__ x)
{
  int n = blockIdx.x, tid = threadIdx.x;
  int m = n & 7;
  __shared__ float sn[512];
  float mu = meanv[n], sd = stdv[n];
  float A = rs[m]/sd, C = rb[m] - mu*A;
  const float* p = series + n*512;
  for(int t=tid;t<512;t+=256) sn[t] = p[t]*A + C;
  __syncthreads();
  float w[16];
  #pragma unroll
  for(int i=0;i<16;i++) w[i] = up_w[i*256+tid];
  ushort* xo = x + n*(NP*256);
  for(int pi=0;pi<NP;pi++){
    float acc=0.f;
    #pragma unroll
    for(int i=0;i<16;i++) acc = fmaf(sn[pi*8+i], w[i], acc);
    xo[pi*256+tid] = f2u(acc);
  }
}

// ---------------- W_od = wo @ down_w (f32) ----------------
__global__ void __launch_bounds__(256) k_wod(const float* __restrict__ wo,
    const float* __restrict__ dw, float* __restrict__ wod)
{
  int i = blockIdx.x, blk = blockIdx.y, tid = threadIdx.x;
  __shared__ float row[512];
  const float* wr = wo + (blk*512 + i)*512;
  for(int k=tid;k<512;k+=256) row[k]=wr[k];
  __syncthreads();
  const float* d = dw + blk*512*256;
  float acc=0.f;
  for(int k=0;k<512;k++) acc = fmaf(row[k], d[k*256+tid], acc);
  wod[(blk*512+i)*256+tid]=acc;
}

// ---------------- transpose wod (512k x 256n) -> wodt bf16 [256][512] ----------------
__global__ void __launch_bounds__(256) k_tr_wodt(const float* __restrict__ wod, ushort* __restrict__ wodt)
{
  __shared__ float tile[32][33];
  int blk = blockIdx.z;
  int n0 = blockIdx.x*32, k0 = blockIdx.y*32;
  int tid = threadIdx.x;
  #pragma unroll
  for(int i=0;i<4;i++){
    int idx = tid + 256*i; int kl = idx>>5, nl = idx&31;
    tile[kl][nl] = wod[blk*512*256 + (k0+kl)*256 + n0+nl];
  }
  __syncthreads();
  #pragma unroll
  for(int i=0;i<4;i++){
    int idx = tid + 256*i; int nl = idx>>5, kl = idx&31;
    wodt[blk*256*512 + (n0+nl)*512 + k0+kl] = f2u(tile[kl][nl]);
  }
}

// ---------------- transpose [wi;wh] (768k x 2048n) -> wt bf16 [2048][768] ----------------
__global__ void __launch_bounds__(256) k_tr_lstmw(const float* __restrict__ wi,
    const float* __restrict__ wh, ushort* __restrict__ wt)
{
  __shared__ float tile[32][33];
  int blk = blockIdx.z;
  int n0 = blockIdx.x*32, k0 = blockIdx.y*32;
  int tid = threadIdx.x;
  #pragma unroll
  for(int i=0;i<4;i++){
    int idx = tid + 256*i; int kl = idx>>5, nl = idx&31;
    int k = k0+kl, n = n0+nl;
    float v = (k<256) ? wi[blk*256*2048 + k*2048 + n]
                      : wh[blk*512*2048 + (k-256)*2048 + n];
    tile[kl][nl] = v;
  }
  __syncthreads();
  #pragma unroll
  for(int i=0;i<4;i++){
    int idx = tid + 256*i; int nl = idx>>5, kl = idx&31;
    wt[blk*2048*768 + (n0+nl)*768 + k0+kl] = f2u(tile[kl][nl]);
  }
}

// ---------------- transpose [wq|wk|wv] (512k x 768n), fold ns[k] -> wqkvt bf16 [768][512] ----------------
__global__ void __launch_bounds__(256) k_tr_qkvw(const float* __restrict__ wq,
    const float* __restrict__ wk, const float* __restrict__ wv,
    const float* __restrict__ ns, ushort* __restrict__ wqkvt)
{
  __shared__ float tile[32][33];
  int blk = blockIdx.z;
  int n0 = blockIdx.x*32, k0 = blockIdx.y*32;
  int tid = threadIdx.x;
  #pragma unroll
  for(int i=0;i<4;i++){
    int idx = tid + 256*i; int kl = idx>>5, nl = idx&31;
    int k = k0+kl, n = n0+nl;
    float v;
    if(n < 512)      v = wq[blk*512*512 + k*512 + n];
    else if(n < 640) v = wk[blk*512*128 + k*128 + (n-512)];
    else             v = wv[blk*512*128 + k*128 + (n-640)];
    tile[kl][nl] = v * ns[blk*512 + k];
  }
  __syncthreads();
  #pragma unroll
  for(int i=0;i<4;i++){
    int idx = tid + 256*i; int nl = idx>>5, kl = idx&31;
    wqkvt[blk*768*512 + (n0+nl)*512 + k0+kl] = f2u(tile[kl][nl]);
  }
}

// ---------------- persistent LSTM scan: all 63 steps in one launch (r3-verified structure) ----------------
// 256 blocks x 256 thr, 1 block/CU (132 KB LDS). Block = (row group g: 64 rows) x (jj tile y: 32 jj x 4 gates).
// Cross-block dep row-local: 16-block group barrier per step via BYTE FLAGS in one 16B line.
// h stores coalesced: epilogue -> LDS staging tile -> one 16B sc1 store/thread.
// wi B-frags in regs; wh (k 256..767) fully LDS-resident, XOR-swizzled. c-state in regs.
// Epilogue gates use HW v_exp/v_rcp. x/h A-operand loads use an explicit 4-deep rolling
// window (8 loads in flight) to hide IC-cold h-load latency (VGPRs are free at 1 wave/SIMD).
__global__ void __launch_bounds__(256,1) k_lstm_scan(
    const ushort* __restrict__ x, ushort* __restrict__ hs,
    const ushort* __restrict__ wt, const float* __restrict__ bias,
    uchar* __restrict__ flags, int tagbase)
{
  __shared__ __align__(16) short Bwh[128*512];     // 128 KB: c row (gate*32+jjl) x k 256..767, swizzled
  __shared__ __align__(16) ushort hstage[64*32];   // 4 KB h staging
  int fb = blockIdx.x;
  // XCD-grouping heuristic: members of a barrier group share blockIdx%8 -> same XCD
  int g = (fb & 7) | ((fb >> 4) & 8);
  int y = (fb >> 3) & 15;
  int n0 = g*64, jj0 = y*32;
  int tid = threadIdx.x;
  int wv = tid>>6, lane = tid&63, quad = lane>>4, l16 = lane&15;
  int wrow = wv>>1, wcol = wv&1;

  // fill Bwh: 128 c-rows x 64 short8 (k 256..767), 16B-block XOR swizzle by (c&7)
  for(int i=tid; i<8192; i+=256){
    int c = i>>6, kb = i&63;
    short8 v = *(const short8*)(wt + ((c>>5)*512 + jj0 + (c&31))*768 + 256 + kb*8);
    *(short8*)((char*)Bwh + c*1024 + ((kb*16) ^ ((c&7)<<4))) = v;
  }
  // wi B-fragments -> regs (4 gates x 8 k-chunks)
  int jj = jj0 + wcol*16 + l16;
  short8 bwi[4][8];
  #pragma unroll
  for(int gg=0; gg<4; gg++){
    const ushort* wp = wt + (gg*512 + jj)*768 + quad*8;
    #pragma unroll
    for(int ck=0; ck<8; ck++) bwi[gg][ck] = *(const short8*)(wp + ck*32);
  }
  float bI=bias[jj], bF=bias[512+jj], bG=bias[1024+jj], bO=bias[1536+jj];
  float cs[2][4];
  #pragma unroll
  for(int a=0;a<2;a++){
    #pragma unroll
    for(int r=0;r<4;r++) cs[a][r]=0.f;
  }
  const ushort* xb0 = x  + (n0 + wrow*32 + l16)*(NP*256) + quad*8;
  const ushort* hb0 = hs + (n0 + wrow*32 + l16)*(NP*512) + quad*8;
  int xorb = (l16&7)<<4;
  uchar* myflag = flags + g*16 + y;
  const uchar* gflags = flags + g*16;
  __syncthreads();

  for(int t=0; t<NP; ++t){
    f32x4 acc[4][2];
    #pragma unroll
    for(int gg=0; gg<4; gg++){ acc[gg][0]=(f32x4){0.f,0.f,0.f,0.f}; acc[gg][1]=(f32x4){0.f,0.f,0.f,0.f}; }

    // ---- x_t @ wi (k 0..255) — no recurrent dep; 4-deep load window ----
    {
      const ushort* xb  = xb0 + t*256;
      const ushort* xb2 = xb + 16*(NP*256);
      short8 v0[4], v1[4];
      #pragma unroll
      for(int p=0;p<4;p++){
        v0[p] = *(const short8*)(xb  + p*32);
        v1[p] = *(const short8*)(xb2 + p*32);
      }
      #pragma unroll
      for(int ck=0; ck<8; ck++){
        short8 a0 = v0[ck&3];
        short8 a1 = v1[ck&3];
        if(ck < 4){
          v0[ck&3] = *(const short8*)(xb  + (ck+4)*32);
          v1[ck&3] = *(const short8*)(xb2 + (ck+4)*32);
        }
        #pragma unroll
        for(int gg=0; gg<4; gg++){
          acc[gg][0] = __builtin_amdgcn_mfma_f32_16x16x32_bf16(a0, bwi[gg][ck], acc[gg][0], 0,0,0);
          acc[gg][1] = __builtin_amdgcn_mfma_f32_16x16x32_bf16(a1, bwi[gg][ck], acc[gg][1], 0,0,0);
        }
      }
    }

    if(t > 0){
      // ---- group barrier: all 16 flag bytes >= tagbase+t (monotonic; '>=' tolerates fast blocks) ----
      if(tid==0){
        uint tag = (uint)(tagbase + t);
        while(1){
          i32x4 f;
          asm volatile("global_load_dwordx4 %0, %1, off sc0 sc1\n\ts_waitcnt vmcnt(0)"
                       : "=&v"(f) : "v"(gflags) : "memory");
          uint ok = 1u;
          #pragma unroll
          for(int q=0;q<4;q++){
            uint w = (uint)f[q];
            if(( w      &0xffu) < tag) ok=0;
            if(((w>>8 ) &0xffu) < tag) ok=0;
            if(((w>>16) &0xffu) < tag) ok=0;
            if( (w>>24)         < tag) ok=0;
          }
          if(ok) break;
          __builtin_amdgcn_s_sleep(1);
        }
      }
      __syncthreads();

      const ushort* hb  = hb0 + (t-1)*512;
      const ushort* hb2 = hb + 16*(NP*512);
      // ---- h @ wh, k 256..767 from LDS; h A-operand via 4-deep load window ----
      short8 w0[4], w1[4];
      #pragma unroll
      for(int p=0;p<4;p++){
        w0[p] = *(const short8*)(hb  + p*32);
        w1[p] = *(const short8*)(hb2 + p*32);
      }
      #pragma unroll
      for(int ck=0; ck<16; ck++){
        short8 a0 = w0[ck&3];
        short8 a1 = w1[ck&3];
        if(ck < 12){
          w0[ck&3] = *(const short8*)(hb  + (ck+4)*32);
          w1[ck&3] = *(const short8*)(hb2 + (ck+4)*32);
        }
        #pragma unroll
        for(int gg=0; gg<4; gg++){
          int c = gg*32 + wcol*16 + l16;
          short8 bh = *(short8*)((char*)Bwh + c*1024 + ((ck*64 + quad*16) ^ xorb));
          acc[gg][0] = __builtin_amdgcn_mfma_f32_16x16x32_bf16(a0, bh, acc[gg][0], 0,0,0);
          acc[gg][1] = __builtin_amdgcn_mfma_f32_16x16x32_bf16(a1, bh, acc[gg][1], 0,0,0);
        }
      }
    }

    // ---- gates (HW exp/rcp) + c-state (regs) + h -> LDS staging (swizzled) ----
    #pragma unroll
    for(int a=0;a<2;a++){
      #pragma unroll
      for(int r=0;r<4;r++){
        int rowl = wrow*32 + a*16 + quad*4 + r;
        float zi=acc[0][a][r]+bI, zf=acc[1][a][r]+bF, zg=acc[2][a][r]+bG, zo=acc[3][a][r]+bO;
        float c = sig_fast(zf)*cs[a][r] + sig_fast(zi)*tanh_fast(zg);
        cs[a][r] = c;
        float hv = sig_fast(zo)*tanh_fast(c);
        int coll = wcol*16 + l16;
        int off = rowl*64 + ((coll*2) ^ (((rowl>>2)&3)<<4));
        *(ushort*)((char*)hstage + off) = f2u(hv);
      }
    }
    __syncthreads();
    // ---- coalesced device-visible h store: 256 threads x 16B ----
    {
      int rowl = tid>>2, c0b = (tid&3)*16;
      int off = rowl*64 + (c0b ^ (((rowl>>2)&3)<<4));
      i32x4 vv = *(const i32x4*)((const char*)hstage + off);
      ushort* gp = hs + ((size_t)(n0+rowl)*NP + t)*512 + jj0 + (tid&3)*8;
      asm volatile("global_store_dwordx4 %0, %1, off sc0 sc1" :: "v"(gp), "v"(vv) : "memory");
    }
    __syncthreads();   // drains vmcnt(0) per wave -> all h stores at coherence point
    if(tid==0 && t < NP-1){
      uint v = (uint)(tagbase + t + 1);
      asm volatile("global_store_byte %0, %1, off sc0 sc1" :: "v"(myflag), "v"(v) : "memory");
    }
  }
}

// ---------------- qkv GEMM via MFMA: 64512 x 768, K=512; 128x128 tile; rms fused ----------------
__global__ void __launch_bounds__(256) k_qkv_m(
    const ushort* __restrict__ hs, const ushort* __restrict__ wqkvt,
    ushort* __restrict__ qkv)
{
  __shared__ short As[128*40];
  __shared__ short Bs[128*40];
  __shared__ float rvs[128];
  int tid = threadIdx.x;
  int r0 = blockIdx.x*128, c0 = blockIdx.y*128;
  int wv = tid>>6, lane = tid&63, quad = lane>>4, l16 = lane&15;
  int wrow = wv>>1, wcol = wv&1;
  int arow0 = tid>>2, akp = tid&3;
  const ushort* aptr[2];
  #pragma unroll
  for(int i=0;i<2;i++){
    int r = r0 + arow0 + i*64;
    int bq = r/8064; int rr = r - bq*8064;
    int m = rr/1008; int rem = rr - m*1008;
    int p = rem>>4; int d = rem&15;
    int n = (bq*16+d)*8+m;
    aptr[i] = hs + (n*NP+p)*512 + akp*8;
  }
  f32x4 acc[4][4];
  #pragma unroll
  for(int b=0;b<4;b++){
    #pragma unroll
    for(int a=0;a<4;a++) acc[b][a] = (f32x4){0.f,0.f,0.f,0.f};
  }
  float ssq0 = 0.f, ssq1 = 0.f;
  for(int k0=0;k0<512;k0+=32){
    {
      short8 av = *(const short8*)(aptr[0] + k0);
      *(short8*)&As[arow0*40 + akp*8] = av;
      #pragma unroll
      for(int e=0;e<8;e++){ float vv = u2f((ushort)av[e]); ssq0 = fmaf(vv, vv, ssq0); }
    }
    {
      short8 av = *(const short8*)(aptr[1] + k0);
      *(short8*)&As[(arow0+64)*40 + akp*8] = av;
      #pragma unroll
      for(int e=0;e<8;e++){ float vv = u2f((ushort)av[e]); ssq1 = fmaf(vv, vv, ssq1); }
    }
    #pragma unroll
    for(int i=0;i<2;i++){
      int pc = tid + 256*i; int rl=pc>>2, kp=pc&3;
      *(short8*)&Bs[rl*40+kp*8] = *(const short8*)(wqkvt + (c0+rl)*512 + k0 + kp*8);
    }
    __syncthreads();
    short8 af[4], bfr[4];
    #pragma unroll
    for(int a=0;a<4;a++) af[a] = *(short8*)&As[(wrow*64 + a*16 + l16)*40 + quad*8];
    #pragma unroll
    for(int b=0;b<4;b++) bfr[b] = *(short8*)&Bs[(wcol*64 + b*16 + l16)*40 + quad*8];
    #pragma unroll
    for(int b=0;b<4;b++){
      #pragma unroll
      for(int a=0;a<4;a++)
        acc[b][a] = __builtin_amdgcn_mfma_f32_16x16x32_bf16(af[a], bfr[b], acc[b][a], 0,0,0);
    }
    __syncthreads();
  }
  ssq0 += __shfl_xor(ssq0, 1); ssq0 += __shfl_xor(ssq0, 2);
  ssq1 += __shfl_xor(ssq1, 1); ssq1 += __shfl_xor(ssq1, 2);
  if(akp==0){
    rvs[arow0]    = rsqrtf(ssq0*(1.f/512.f)+1e-6f);
    rvs[arow0+64] = rsqrtf(ssq1*(1.f/512.f)+1e-6f);
  }
  __syncthreads();
  #pragma unroll
  for(int a=0;a<4;a++){
    #pragma unroll
    for(int rg=0;rg<4;rg++){
      int rowl = wrow*64 + a*16 + quad*4 + rg;
      int rw = r0 + rowl;
      float rv = rvs[rowl];
      #pragma unroll
      for(int b=0;b<4;b++){
        int c = c0 + wcol*64 + b*16 + l16;
        qkv[rw*768 + c] = f2u(acc[b][a][rg] * rv);
      }
    }
  }
}

// ---------------- attention: one block per 16-row group, all 8 heads (LDS-staged qkv tile) ----------------
__global__ void __launch_bounds__(256) k_attn(ushort* __restrict__ qkv)
{
  int r3 = blockIdx.x;
  int tid = threadIdx.x;
  __shared__ ushort qk[16*768];    // 24 KB bf16 tile (q|k|v for 16 rows)
  __shared__ float qs[16][64];
  __shared__ float ks[16][65];
  __shared__ float vs[16][64];
  __shared__ float P[16][17];
  ushort* base = qkv + r3*16*768;
  // stage the whole 16x768 tile once (coalesced 16B loads)
  for(int i=tid; i<1536; i+=256)
    *(short8*)&qk[i*8] = *(const short8*)&base[i*8];
  __syncthreads();
  int xx = tid&63, s4 = tid>>6;
  int i = tid>>4, j = tid&15;
  for(int h=0; h<8; h++){
    int kvh = (h>>2)*64;
    #pragma unroll
    for(int a=0;a<4;a++){
      int s = s4 + 4*a;
      qs[s][xx] = u2f(qk[s*768 + h*64 + xx]);
      ks[s][xx] = u2f(qk[s*768 + 512 + kvh + xx]);
      vs[s][xx] = u2f(qk[s*768 + 640 + kvh + xx]);
    }
    __syncthreads();
    float sc = 0.f;
    #pragma unroll
    for(int xq=0;xq<64;xq++) sc = fmaf(qs[i][xq], ks[j][xq], sc);
    P[i][j] = sc*0.125f;
    __syncthreads();
    float row[16];
    #pragma unroll
    for(int jj=0;jj<16;jj++) row[jj] = P[i][jj];
    float mx = row[0];
    #pragma unroll
    for(int jj=1;jj<16;jj++) mx = fmaxf(mx, row[jj]);
    float sum = 0.f;
    #pragma unroll
    for(int jj=0;jj<16;jj++) sum += expf(row[jj]-mx);
    float pme = expf(row[j]-mx)/sum;
    __syncthreads();
    P[i][j] = pme;
    __syncthreads();
    #pragma unroll
    for(int a=0;a<4;a++){
      int s = s4 + 4*a;
      float o = 0.f;
      #pragma unroll
      for(int jj=0;jj<16;jj++) o = fmaf(P[s][jj], vs[jj][xx], o);
      base[s*768 + h*64 + xx] = f2u(o);   // disjoint cols per head; q re-read from LDS copy
    }
    __syncthreads();   // protect qs/ks/vs/P before next head
  }
}

// ---------------- bel GEMM via MFMA: O(64512x512 in qkv) @ wodt^T -> scatter bf16 xbuf ----------------
__global__ void __launch_bounds__(256) k_bel_m(
    const ushort* __restrict__ qkv, const ushort* __restrict__ wodt,
    ushort* __restrict__ x)
{
  __shared__ short As[128*40];
  __shared__ short Bs[128*40];
  int tid = threadIdx.x;
  int r0 = blockIdx.x*128, c0 = blockIdx.y*128;
  int wv = tid>>6, lane = tid&63, quad = lane>>4, l16 = lane&15;
  int wrow = wv>>1, wcol = wv&1;
  int arow0 = tid>>2, akp = tid&3;
  const ushort* aptr0 = qkv + (r0+arow0)*768 + akp*8;
  const ushort* aptr1 = qkv + (r0+arow0+64)*768 + akp*8;
  f32x4 acc[4][4];
  #pragma unroll
  for(int b=0;b<4;b++){
    #pragma unroll
    for(int a=0;a<4;a++) acc[b][a] = (f32x4){0.f,0.f,0.f,0.f};
  }
  for(int k0=0;k0<512;k0+=32){
    *(short8*)&As[arow0*40 + akp*8]      = *(const short8*)(aptr0 + k0);
    *(short8*)&As[(arow0+64)*40 + akp*8] = *(const short8*)(aptr1 + k0);
    #pragma unroll
    for(int i=0;i<2;i++){
      int pc = tid + 256*i; int rl=pc>>2, kp=pc&3;
      *(short8*)&Bs[rl*40+kp*8] = *(const short8*)(wodt + (c0+rl)*512 + k0 + kp*8);
    }
    __syncthreads();
    short8 af[4], bfr[4];
    #pragma unroll
    for(int a=0;a<4;a++) af[a] = *(short8*)&As[(wrow*64 + a*16 + l16)*40 + quad*8];
    #pragma unroll
    for(int b=0;b<4;b++) bfr[b] = *(short8*)&Bs[(wcol*64 + b*16 + l16)*40 + quad*8];
    #pragma unroll
    for(int b=0;b<4;b++){
      #pragma unroll
      for(int a=0;a<4;a++)
        acc[b][a] = __builtin_amdgcn_mfma_f32_16x16x32_bf16(af[a], bfr[b], acc[b][a], 0,0,0);
    }
    __syncthreads();
  }
  #pragma unroll
  for(int a=0;a<4;a++){
    #pragma unroll
    for(int rg=0;rg<4;rg++){
      int rw = r0 + wrow*64 + a*16 + quad*4 + rg;
      int bq = rw/8064; int rr = rw - bq*8064;
      int m = rr/1008; int rem = rr - m*1008;
      int p = rem>>4; int d = rem&15;
      int n = (bq*16+d)*8+m;
      ushort* xo = x + (n*NP+p)*256;
      #pragma unroll
      for(int b=0;b<4;b++){
        int c = c0 + wcol*64 + b*16 + l16;
        xo[c] = f2u(acc[b][a][rg]);
      }
    }
  }
}

// ---------------- head ----------------
__global__ void __launch_bounds__(256) k_head(const ushort* __restrict__ x,
    const float* __restrict__ meanv, const float* __restrict__ stdv,
    const float* __restrict__ rs, const float* __restrict__ rb,
    const float* __restrict__ hns, const float* __restrict__ pw,
    const float* __restrict__ qw, float* __restrict__ out)
{
  int n = blockIdx.x, tid = threadIdx.x;
  __shared__ float nb[256];
  __shared__ float red[256];
  float v = u2f(x[(n*NP + 62)*256 + tid]);
  red[tid] = v*v; __syncthreads();
  for(int s=128;s>0;s>>=1){
    if(tid<s) red[tid]+=red[tid+s];
    __syncthreads();
  }
  float rinv = rsqrtf(red[0]*(1.f/256.f)+1e-6f);
  nb[tid] = v*rinv*hns[tid];
  __syncthreads();
  int m = n&7;
  float mu=meanv[n], sd=stdv[n], sc=rs[m], bi=rb[m];
  for(int col=tid; col<384; col+=256){
    float acc=0.f;
    int slot, hh;
    if(col < 96){
      for(int k=0;k<256;k++) acc = fmaf(nb[k], pw[k*96+col], acc);
      slot = 0; hh = col;
    } else {
      int cq = col-96;
      for(int k=0;k<256;k++) acc = fmaf(nb[k], qw[k*288+cq], acc);
      int qi = cq - (cq/3)*3;
      slot = 1 + qi; hh = cq/3;
    }
    float y = (acc - bi)/sc*sd + mu;
    out[(slot*1024 + n)*96 + hh] = y;
  }
}

extern "C" void kernel_launch(void* const* d_in, const int* in_sizes, int n_in,
                              void* d_out, int out_size, void* d_ws, size_t ws_size,
                              hipStream_t stream)
{
  const float* series    = (const float*)d_in[0];
  const float* rs        = (const float*)d_in[1];
  const float* rb        = (const float*)d_in[2];
  const float* up_w      = (const float*)d_in[3];
  const float* lstm_wi   = (const float*)d_in[4];
  const float* lstm_wh   = (const float*)d_in[5];
  const float* lstm_b    = (const float*)d_in[6];
  const float* norm_scale= (const float*)d_in[7];
  const float* wq        = (const float*)d_in[8];
  const float* wk        = (const float*)d_in[9];
  const float* wv        = (const float*)d_in[10];
  const float* wo        = (const float*)d_in[11];
  const float* down_w    = (const float*)d_in[12];
  const float* head_ns   = (const float*)d_in[13];
  const float* point_w   = (const float*)d_in[14];
  const float* quant_w   = (const float*)d_in[15];
  float* out = (float*)d_out;

  float* ws = (float*)d_ws;
  float*  meanv = ws;                       // 1024
  float*  stdv  = meanv + 1024;             // 1024
  float*  rmsi  = stdv  + 1024;             // 64512 (unused; layout stability)
  float*  cst   = rmsi  + 64512;            // 524288 (start reused for flag bytes)
  float*  wodf  = cst   + 524288;           // 524288
  ushort* xbuf  = (ushort*)(wodf + 524288);         // 16515072 bf16
  ushort* hsb   = xbuf  + 16515072;                 // 33030144 bf16
  ushort* qkvb  = hsb   + 33030144;                 // 49545216 bf16
  ushort* wt    = qkvb  + 49545216;                 // 6291456 bf16
  ushort* wqkvt = wt    + 6291456;                  // 1572864 bf16
  ushort* wodt  = wqkvt + 1572864;                  // 524288 bf16
  int*    bar   = (int*)cst;                        // 256 flag bytes (16 groups x 16 blocks)

  k_revin<<<1024,256,0,stream>>>(series, meanv, stdv, bar);
  k_patch<<<1024,256,0,stream>>>(series, rs, rb, up_w, meanv, stdv, xbuf);
  k_wod<<<dim3(512,4),256,0,stream>>>(wo, down_w, wodf);
  k_tr_wodt<<<dim3(8,16,4),256,0,stream>>>(wodf, wodt);
  k_tr_lstmw<<<dim3(64,24,4),256,0,stream>>>(lstm_wi, lstm_wh, wt);
  k_tr_qkvw<<<dim3(24,16,4),256,0,stream>>>(wq, wk, wv, norm_scale, wqkvt);

  for(int blk=0; blk<4; blk++){
    const ushort* wt_b = wt + blk*2048*768;
    const float*  bb   = lstm_b + blk*2048;
    k_lstm_scan<<<256,256,0,stream>>>(xbuf, hsb, wt_b, bb, (uchar*)bar, blk*NP);
    k_qkv_m<<<dim3(504,6),256,0,stream>>>(hsb, wqkvt + blk*768*512, qkvb);
    k_attn<<<4032,256,0,stream>>>(qkvb);
    k_bel_m<<<dim3(504,2),256,0,stream>>>(qkvb, wodt + blk*256*512, xbuf);
  }
  k_head<<<1024,256,0,stream>>>(xbuf, meanv, stdv, rs, rb, head_ns, point_w, quant_w, out);
}

// Round 12
// 3143.046 us; speedup vs baseline: 1.0647x; 1.0647x over previous
//
#include <hip/hip_runtime.h>
#include <hip/hip_bf16.h>

#define NP 63   // number of patches

typedef __attribute__((ext_vector_type(8))) short short8;
typedef __attribute__((ext_vector_type(4))) float f32x4;
typedef __attribute__((ext_vector_type(4))) int i32x4;
typedef unsigned char uchar;

__device__ __forceinline__ float sigf(float x){ return 1.0f/(1.0f+expf(-x)); }
__device__ __forceinline__ float u2f(ushort u){ __hip_bfloat16 h; *(ushort*)&h = u; return __bfloat162float(h); }
__device__ __forceinline__ ushort f2u(float f){ __hip_bfloat16 h = __float2bfloat16(f); return *(ushort*)&h; }

// HW transcendental gate functions (scan epilogue critical path):
// v_exp_f32 = 2^x (1 ulp), v_rcp_f32 (~22-bit). Args clamped to +-126 for inf-safety.
__device__ __forceinline__ float fexp2(float x){ float r; asm("v_exp_f32 %0, %1" : "=v"(r) : "v"(x)); return r; }
__device__ __forceinline__ float frcp (float x){ float r; asm("v_rcp_f32 %0, %1" : "=v"(r) : "v"(x)); return r; }
#define LOG2E 1.442695040888963f
__device__ __forceinline__ float sig_fast(float x){
  float a = fminf(fmaxf(-LOG2E*x, -126.f), 126.f);
  return frcp(1.f + fexp2(a));
}
__device__ __forceinline__ float tanh_fast(float x){
  float a = fminf(fmaxf(-2.f*LOG2E*x, -126.f), 126.f);
  float e = fexp2(a);
  return (1.f - e) * frcp(1.f + e);
}

// ---------------- RevIN stats (+ zero persistent-scan flag bytes) ----------------
__global__ void __launch_bounds__(256) k_revin(const float* __restrict__ series,
    float* __restrict__ meanv, float* __restrict__ stdv, int* __restrict__ bar)
{
  int n = blockIdx.x, tid = threadIdx.x;
  if(n==0 && tid<64) bar[tid] = 0;   // 256 flag bytes (16 groups x 16 blocks)
  __shared__ float s1[256], s2[256];
  const float* p = series + n*512;
  float a = 0.f, b = 0.f;
  for(int t=tid;t<512;t+=256){ float v=p[t]; a+=v; b+=v*v; }
  s1[tid]=a; s2[tid]=b; __syncthreads();
  for(int s=128;s>0;s>>=1){
    if(tid<s){ s1[tid]+=s1[tid+s]; s2[tid]+=s2[tid+s]; }
    __syncthreads();
  }
  if(tid==0){
    float mu = s1[0]*(1.f/512.f);
    float var = fmaxf(s2[0]*(1.f/512.f) - mu*mu, 0.f);
    meanv[n]=mu; stdv[n]=sqrtf(var+1e-5f);
  }
}

// ---------------- patch embed -> bf16 xbuf ----------------
__global__ void __launch_bounds__(256) k_patch(const float* __restrict__ series,
    const float* __restrict__ rs, const float* __restrict__ rb,
    const float* __restrict__ up_w, const float* __restrict__ meanv,
    const float* __restrict__ stdv, ushort* __restrict__ x)
{
  int n = blockIdx.x, tid = threadIdx.x;
  int m = n & 7;
  __shared__ float sn[512];
  float mu = meanv[n], sd = stdv[n];
  float A = rs[m]/sd, C = rb[m] - mu*A;
  const float* p = series + n*512;
  for(int t=tid;t<512;t+=256) sn[t] = p[t]*A + C;
  __syncthreads();
  float w[16];
  #pragma unroll
  for(int i=0;i<16;i++) w[i] = up_w[i*256+tid];
  ushort* xo = x + n*(NP*256);
  for(int pi=0;pi<NP;pi++){
    float acc=0.f;
    #pragma unroll
    for(int i=0;i<16;i++) acc = fmaf(sn[pi*8+i], w[i], acc);
    xo[pi*256+tid] = f2u(acc);
  }
}

// ---------------- W_od = wo @ down_w (f32) ----------------
__global__ void __launch_bounds__(256) k_wod(const float* __restrict__ wo,
    const float* __restrict__ dw, float* __restrict__ wod)
{
  int i = blockIdx.x, blk = blockIdx.y, tid = threadIdx.x;
  __shared__ float row[512];
  const float* wr = wo + (blk*512 + i)*512;
  for(int k=tid;k<512;k+=256) row[k]=wr[k];
  __syncthreads();
  const float* d = dw + blk*512*256;
  float acc=0.f;
  for(int k=0;k<512;k++) acc = fmaf(row[k], d[k*256+tid], acc);
  wod[(blk*512+i)*256+tid]=acc;
}

// ---------------- transpose wod (512k x 256n) -> wodt bf16 [256][512] ----------------
__global__ void __launch_bounds__(256) k_tr_wodt(const float* __restrict__ wod, ushort* __restrict__ wodt)
{
  __shared__ float tile[32][33];
  int blk = blockIdx.z;
  int n0 = blockIdx.x*32, k0 = blockIdx.y*32;
  int tid = threadIdx.x;
  #pragma unroll
  for(int i=0;i<4;i++){
    int idx = tid + 256*i; int kl = idx>>5, nl = idx&31;
    tile[kl][nl] = wod[blk*512*256 + (k0+kl)*256 + n0+nl];
  }
  __syncthreads();
  #pragma unroll
  for(int i=0;i<4;i++){
    int idx = tid + 256*i; int nl = idx>>5, kl = idx&31;
    wodt[blk*256*512 + (n0+nl)*512 + k0+kl] = f2u(tile[kl][nl]);
  }
}

// ---------------- transpose [wi;wh] (768k x 2048n) -> wt bf16 [2048][768] ----------------
__global__ void __launch_bounds__(256) k_tr_lstmw(const float* __restrict__ wi,
    const float* __restrict__ wh, ushort* __restrict__ wt)
{
  __shared__ float tile[32][33];
  int blk = blockIdx.z;
  int n0 = blockIdx.x*32, k0 = blockIdx.y*32;
  int tid = threadIdx.x;
  #pragma unroll
  for(int i=0;i<4;i++){
    int idx = tid + 256*i; int kl = idx>>5, nl = idx&31;
    int k = k0+kl, n = n0+nl;
    float v = (k<256) ? wi[blk*256*2048 + k*2048 + n]
                      : wh[blk*512*2048 + (k-256)*2048 + n];
    tile[kl][nl] = v;
  }
  __syncthreads();
  #pragma unroll
  for(int i=0;i<4;i++){
    int idx = tid + 256*i; int nl = idx>>5, kl = idx&31;
    wt[blk*2048*768 + (n0+nl)*768 + k0+kl] = f2u(tile[kl][nl]);
  }
}

// ---------------- transpose [wq|wk|wv] (512k x 768n), fold ns[k] -> wqkvt bf16 [768][512] ----------------
__global__ void __launch_bounds__(256) k_tr_qkvw(const float* __restrict__ wq,
    const float* __restrict__ wk, const float* __restrict__ wv,
    const float* __restrict__ ns, ushort* __restrict__ wqkvt)
{
  __shared__ float tile[32][33];
  int blk = blockIdx.z;
  int n0 = blockIdx.x*32, k0 = blockIdx.y*32;
  int tid = threadIdx.x;
  #pragma unroll
  for(int i=0;i<4;i++){
    int idx = tid + 256*i; int kl = idx>>5, nl = idx&31;
    int k = k0+kl, n = n0+nl;
    float v;
    if(n < 512)      v = wq[blk*512*512 + k*512 + n];
    else if(n < 640) v = wk[blk*512*128 + k*128 + (n-512)];
    else             v = wv[blk*512*128 + k*128 + (n-640)];
    tile[kl][nl] = v * ns[blk*512 + k];
  }
  __syncthreads();
  #pragma unroll
  for(int i=0;i<4;i++){
    int idx = tid + 256*i; int nl = idx>>5, kl = idx&31;
    wqkvt[blk*768*512 + (n0+nl)*512 + k0+kl] = f2u(tile[kl][nl]);
  }
}

// ---------------- persistent LSTM scan: all 63 steps in one launch (r3 structure, XCD-local sync) ----------------
// 256 blocks x 256 thr, 1 block/CU (132 KB LDS). Block = (row group g: 64 rows) x (jj tile y: 32 jj x 4 gates).
// ALL 16 members of a barrier group share fb%8 == XCD (round-robin dispatch, 1 block/CU) -> the
// entire per-step h/flag exchange stays in the shared per-XCD L2: PLAIN h stores (L2 ack ~3x faster
// than sc1 IC write-through), PLAIN flag stores, sc0-only polls (bypass L1, hit local L2).
// Cross-launch visibility: end-of-kernel L2 writeback (same mechanism that publishes xbuf/qkvb today);
// monotonic tags (tagbase) make replay safe. Epilogue gates use HW v_exp/v_rcp.
__global__ void __launch_bounds__(256,1) k_lstm_scan(
    const ushort* __restrict__ x, ushort* __restrict__ hs,
    const ushort* __restrict__ wt, const float* __restrict__ bias,
    uchar* __restrict__ flags, int tagbase)
{
  __shared__ __align__(16) short Bwh[128*512];     // 128 KB: c row (gate*32+jjl) x k 256..767, swizzled
  __shared__ __align__(16) ushort hstage[64*32];   // 4 KB h staging
  int fb = blockIdx.x;
  // group members share fb&7 -> same XCD; (fb>>4)&8 picks which half of the row space
  int g = (fb & 7) | ((fb >> 4) & 8);
  int y = (fb >> 3) & 15;
  int n0 = g*64, jj0 = y*32;
  int tid = threadIdx.x;
  int wv = tid>>6, lane = tid&63, quad = lane>>4, l16 = lane&15;
  int wrow = wv>>1, wcol = wv&1;

  // fill Bwh: 128 c-rows x 64 short8 (k 256..767), 16B-block XOR swizzle by (c&7)
  for(int i=tid; i<8192; i+=256){
    int c = i>>6, kb = i&63;
    short8 v = *(const short8*)(wt + ((c>>5)*512 + jj0 + (c&31))*768 + 256 + kb*8);
    *(short8*)((char*)Bwh + c*1024 + ((kb*16) ^ ((c&7)<<4))) = v;
  }
  // wi B-fragments -> regs (4 gates x 8 k-chunks)
  int jj = jj0 + wcol*16 + l16;
  short8 bwi[4][8];
  #pragma unroll
  for(int gg=0; gg<4; gg++){
    const ushort* wp = wt + (gg*512 + jj)*768 + quad*8;
    #pragma unroll
    for(int ck=0; ck<8; ck++) bwi[gg][ck] = *(const short8*)(wp + ck*32);
  }
  float bI=bias[jj], bF=bias[512+jj], bG=bias[1024+jj], bO=bias[1536+jj];
  float cs[2][4];
  #pragma unroll
  for(int a=0;a<2;a++){
    #pragma unroll
    for(int r=0;r<4;r++) cs[a][r]=0.f;
  }
  const ushort* xb0 = x  + (n0 + wrow*32 + l16)*(NP*256) + quad*8;
  const ushort* hb0 = hs + (n0 + wrow*32 + l16)*(NP*512) + quad*8;
  int xorb = (l16&7)<<4;
  uchar* myflag = flags + g*16 + y;
  const uchar* gflags = flags + g*16;
  __syncthreads();

  for(int t=0; t<NP; ++t){
    f32x4 acc[4][2];
    #pragma unroll
    for(int gg=0; gg<4; gg++){ acc[gg][0]=(f32x4){0.f,0.f,0.f,0.f}; acc[gg][1]=(f32x4){0.f,0.f,0.f,0.f}; }

    // ---- x_t @ wi (k 0..255) — no recurrent dep, runs before the group wait ----
    #pragma unroll
    for(int ck=0; ck<8; ck++){
      short8 a0 = *(const short8*)(xb0 + t*256 + ck*32);
      short8 a1 = *(const short8*)(xb0 + 16*(NP*256) + t*256 + ck*32);
      #pragma unroll
      for(int gg=0; gg<4; gg++){
        acc[gg][0] = __builtin_amdgcn_mfma_f32_16x16x32_bf16(a0, bwi[gg][ck], acc[gg][0], 0,0,0);
        acc[gg][1] = __builtin_amdgcn_mfma_f32_16x16x32_bf16(a1, bwi[gg][ck], acc[gg][1], 0,0,0);
      }
    }

    if(t > 0){
      // ---- group barrier: all 16 flag bytes >= tagbase+t (monotonic); sc0 poll hits shared L2 ----
      if(tid==0){
        uint tag = (uint)(tagbase + t);
        while(1){
          i32x4 f;
          asm volatile("global_load_dwordx4 %0, %1, off sc0\n\ts_waitcnt vmcnt(0)"
                       : "=&v"(f) : "v"(gflags) : "memory");
          uint ok = 1u;
          #pragma unroll
          for(int q=0;q<4;q++){
            uint w = (uint)f[q];
            if(( w      &0xffu) < tag) ok=0;
            if(((w>>8 ) &0xffu) < tag) ok=0;
            if(((w>>16) &0xffu) < tag) ok=0;
            if( (w>>24)         < tag) ok=0;
          }
          if(ok) break;
          __builtin_amdgcn_s_sleep(1);
        }
      }
      __syncthreads();

      const ushort* hb = hb0 + (t-1)*512;
      // ---- h @ wh, k 256..767 entirely from LDS ----
      #pragma unroll
      for(int ck=0; ck<16; ck++){
        short8 a0 = *(const short8*)(hb + ck*32);
        short8 a1 = *(const short8*)(hb + 16*(NP*512) + ck*32);
        #pragma unroll
        for(int gg=0; gg<4; gg++){
          int c = gg*32 + wcol*16 + l16;
          short8 bh = *(short8*)((char*)Bwh + c*1024 + ((ck*64 + quad*16) ^ xorb));
          acc[gg][0] = __builtin_amdgcn_mfma_f32_16x16x32_bf16(a0, bh, acc[gg][0], 0,0,0);
          acc[gg][1] = __builtin_amdgcn_mfma_f32_16x16x32_bf16(a1, bh, acc[gg][1], 0,0,0);
        }
      }
    }

    // ---- gates (HW exp/rcp) + c-state (regs) + h -> LDS staging (swizzled) ----
    #pragma unroll
    for(int a=0;a<2;a++){
      #pragma unroll
      for(int r=0;r<4;r++){
        int rowl = wrow*32 + a*16 + quad*4 + r;
        float zi=acc[0][a][r]+bI, zf=acc[1][a][r]+bF, zg=acc[2][a][r]+bG, zo=acc[3][a][r]+bO;
        float c = sig_fast(zf)*cs[a][r] + sig_fast(zi)*tanh_fast(zg);
        cs[a][r] = c;
        float hv = sig_fast(zo)*tanh_fast(c);
        int coll = wcol*16 + l16;
        int off = rowl*64 + ((coll*2) ^ (((rowl>>2)&3)<<4));
        *(ushort*)((char*)hstage + off) = f2u(hv);
      }
    }
    __syncthreads();
    // ---- coalesced h store: 256 threads x 16B, PLAIN (lands in shared per-XCD L2) ----
    {
      int rowl = tid>>2, c0b = (tid&3)*16;
      int off = rowl*64 + (c0b ^ (((rowl>>2)&3)<<4));
      i32x4 vv = *(const i32x4*)((const char*)hstage + off);
      ushort* gp = hs + ((size_t)(n0+rowl)*NP + t)*512 + jj0 + (tid&3)*8;
      asm volatile("global_store_dwordx4 %0, %1, off" :: "v"(gp), "v"(vv) : "memory");
    }
    __syncthreads();   // drains vmcnt(0) per wave -> all h stores ack'd in L2
    if(tid==0 && t < NP-1){
      uint v = (uint)(tagbase + t + 1);
      asm volatile("global_store_byte %0, %1, off" :: "v"(myflag), "v"(v) : "memory");
    }
  }
}

// ---------------- qkv GEMM via MFMA: 64512 x 768, K=512; 128x128 tile; rms fused ----------------
__global__ void __launch_bounds__(256) k_qkv_m(
    const ushort* __restrict__ hs, const ushort* __restrict__ wqkvt,
    ushort* __restrict__ qkv)
{
  __shared__ short As[128*40];
  __shared__ short Bs[128*40];
  __shared__ float rvs[128];
  int tid = threadIdx.x;
  int r0 = blockIdx.x*128, c0 = blockIdx.y*128;
  int wv = tid>>6, lane = tid&63, quad = lane>>4, l16 = lane&15;
  int wrow = wv>>1, wcol = wv&1;
  int arow0 = tid>>2, akp = tid&3;
  const ushort* aptr[2];
  #pragma unroll
  for(int i=0;i<2;i++){
    int r = r0 + arow0 + i*64;
    int bq = r/8064; int rr = r - bq*8064;
    int m = rr/1008; int rem = rr - m*1008;
    int p = rem>>4; int d = rem&15;
    int n = (bq*16+d)*8+m;
    aptr[i] = hs + (n*NP+p)*512 + akp*8;
  }
  f32x4 acc[4][4];
  #pragma unroll
  for(int b=0;b<4;b++){
    #pragma unroll
    for(int a=0;a<4;a++) acc[b][a] = (f32x4){0.f,0.f,0.f,0.f};
  }
  float ssq0 = 0.f, ssq1 = 0.f;
  for(int k0=0;k0<512;k0+=32){
    {
      short8 av = *(const short8*)(aptr[0] + k0);
      *(short8*)&As[arow0*40 + akp*8] = av;
      #pragma unroll
      for(int e=0;e<8;e++){ float vv = u2f((ushort)av[e]); ssq0 = fmaf(vv, vv, ssq0); }
    }
    {
      short8 av = *(const short8*)(aptr[1] + k0);
      *(short8*)&As[(arow0+64)*40 + akp*8] = av;
      #pragma unroll
      for(int e=0;e<8;e++){ float vv = u2f((ushort)av[e]); ssq1 = fmaf(vv, vv, ssq1); }
    }
    #pragma unroll
    for(int i=0;i<2;i++){
      int pc = tid + 256*i; int rl=pc>>2, kp=pc&3;
      *(short8*)&Bs[rl*40+kp*8] = *(const short8*)(wqkvt + (c0+rl)*512 + k0 + kp*8);
    }
    __syncthreads();
    short8 af[4], bfr[4];
    #pragma unroll
    for(int a=0;a<4;a++) af[a] = *(short8*)&As[(wrow*64 + a*16 + l16)*40 + quad*8];
    #pragma unroll
    for(int b=0;b<4;b++) bfr[b] = *(short8*)&Bs[(wcol*64 + b*16 + l16)*40 + quad*8];
    #pragma unroll
    for(int b=0;b<4;b++){
      #pragma unroll
      for(int a=0;a<4;a++)
        acc[b][a] = __builtin_amdgcn_mfma_f32_16x16x32_bf16(af[a], bfr[b], acc[b][a], 0,0,0);
    }
    __syncthreads();
  }
  ssq0 += __shfl_xor(ssq0, 1); ssq0 += __shfl_xor(ssq0, 2);
  ssq1 += __shfl_xor(ssq1, 1); ssq1 += __shfl_xor(ssq1, 2);
  if(akp==0){
    rvs[arow0]    = rsqrtf(ssq0*(1.f/512.f)+1e-6f);
    rvs[arow0+64] = rsqrtf(ssq1*(1.f/512.f)+1e-6f);
  }
  __syncthreads();
  #pragma unroll
  for(int a=0;a<4;a++){
    #pragma unroll
    for(int rg=0;rg<4;rg++){
      int rowl = wrow*64 + a*16 + quad*4 + rg;
      int rw = r0 + rowl;
      float rv = rvs[rowl];
      #pragma unroll
      for(int b=0;b<4;b++){
        int c = c0 + wcol*64 + b*16 + l16;
        qkv[rw*768 + c] = f2u(acc[b][a][rg] * rv);
      }
    }
  }
}

// ---------------- attention (bf16 qkv buffer): per (row16-group, head) ----------------
__global__ void __launch_bounds__(256) k_attn(ushort* __restrict__ qkv)
{
  int r3 = blockIdx.x, h = blockIdx.y;
  int tid = threadIdx.x;
  __shared__ float qs[16][64];
  __shared__ float ks[16][65];
  __shared__ float vs[16][64];
  __shared__ float P[16][17];
  ushort* base = qkv + r3*16*768;
  int xx = tid&63, s4 = tid>>6;
  int kvh = (h>>2)*64;
  #pragma unroll
  for(int a=0;a<4;a++){
    int s = s4 + 4*a;
    qs[s][xx] = u2f(base[s*768 + h*64 + xx]);
    ks[s][xx] = u2f(base[s*768 + 512 + kvh + xx]);
    vs[s][xx] = u2f(base[s*768 + 640 + kvh + xx]);
  }
  __syncthreads();
  int i = tid>>4, j = tid&15;
  float sc = 0.f;
  #pragma unroll
  for(int xq=0;xq<64;xq++) sc = fmaf(qs[i][xq], ks[j][xq], sc);
  P[i][j] = sc*0.125f;
  __syncthreads();
  float row[16];
  #pragma unroll
  for(int jj=0;jj<16;jj++) row[jj] = P[i][jj];
  float mx = row[0];
  #pragma unroll
  for(int jj=1;jj<16;jj++) mx = fmaxf(mx, row[jj]);
  float sum = 0.f;
  #pragma unroll
  for(int jj=0;jj<16;jj++) sum += expf(row[jj]-mx);
  float pme = expf(row[j]-mx)/sum;
  __syncthreads();
  P[i][j] = pme;
  __syncthreads();
  #pragma unroll
  for(int a=0;a<4;a++){
    int s = s4 + 4*a;
    float o = 0.f;
    #pragma unroll
    for(int jj=0;jj<16;jj++) o = fmaf(P[s][jj], vs[jj][xx], o);
    base[s*768 + h*64 + xx] = f2u(o);
  }
}

// ---------------- bel GEMM via MFMA: O(64512x512 in qkv) @ wodt^T -> scatter bf16 xbuf ----------------
__global__ void __launch_bounds__(256) k_bel_m(
    const ushort* __restrict__ qkv, const ushort* __restrict__ wodt,
    ushort* __restrict__ x)
{
  __shared__ short As[128*40];
  __shared__ short Bs[128*40];
  int tid = threadIdx.x;
  int r0 = blockIdx.x*128, c0 = blockIdx.y*128;
  int wv = tid>>6, lane = tid&63, quad = lane>>4, l16 = lane&15;
  int wrow = wv>>1, wcol = wv&1;
  int arow0 = tid>>2, akp = tid&3;
  const ushort* aptr0 = qkv + (r0+arow0)*768 + akp*8;
  const ushort* aptr1 = qkv + (r0+arow0+64)*768 + akp*8;
  f32x4 acc[4][4];
  #pragma unroll
  for(int b=0;b<4;b++){
    #pragma unroll
    for(int a=0;a<4;a++) acc[b][a] = (f32x4){0.f,0.f,0.f,0.f};
  }
  for(int k0=0;k0<512;k0+=32){
    *(short8*)&As[arow0*40 + akp*8]      = *(const short8*)(aptr0 + k0);
    *(short8*)&As[(arow0+64)*40 + akp*8] = *(const short8*)(aptr1 + k0);
    #pragma unroll
    for(int i=0;i<2;i++){
      int pc = tid + 256*i; int rl=pc>>2, kp=pc&3;
      *(short8*)&Bs[rl*40+kp*8] = *(const short8*)(wodt + (c0+rl)*512 + k0 + kp*8);
    }
    __syncthreads();
    short8 af[4], bfr[4];
    #pragma unroll
    for(int a=0;a<4;a++) af[a] = *(short8*)&As[(wrow*64 + a*16 + l16)*40 + quad*8];
    #pragma unroll
    for(int b=0;b<4;b++) bfr[b] = *(short8*)&Bs[(wcol*64 + b*16 + l16)*40 + quad*8];
    #pragma unroll
    for(int b=0;b<4;b++){
      #pragma unroll
      for(int a=0;a<4;a++)
        acc[b][a] = __builtin_amdgcn_mfma_f32_16x16x32_bf16(af[a], bfr[b], acc[b][a], 0,0,0);
    }
    __syncthreads();
  }
  #pragma unroll
  for(int a=0;a<4;a++){
    #pragma unroll
    for(int rg=0;rg<4;rg++){
      int rw = r0 + wrow*64 + a*16 + quad*4 + rg;
      int bq = rw/8064; int rr = rw - bq*8064;
      int m = rr/1008; int rem = rr - m*1008;
      int p = rem>>4; int d = rem&15;
      int n = (bq*16+d)*8+m;
      ushort* xo = x + (n*NP+p)*256;
      #pragma unroll
      for(int b=0;b<4;b++){
        int c = c0 + wcol*64 + b*16 + l16;
        xo[c] = f2u(acc[b][a][rg]);
      }
    }
  }
}

// ---------------- head ----------------
__global__ void __launch_bounds__(256) k_head(const ushort* __restrict__ x,
    const float* __restrict__ meanv, const float* __restrict__ stdv,
    const float* __restrict__ rs, const float* __restrict__ rb,
    const float* __restrict__ hns, const float* __restrict__ pw,
    const float* __restrict__ qw, float* __restrict__ out)
{
  int n = blockIdx.x, tid = threadIdx.x;
  __shared__ float nb[256];
  __shared__ float red[256];
  float v = u2f(x[(n*NP + 62)*256 + tid]);
  red[tid] = v*v; __syncthreads();
  for(int s=128;s>0;s>>=1){
    if(tid<s) red[tid]+=red[tid+s];
    __syncthreads();
  }
  float rinv = rsqrtf(red[0]*(1.f/256.f)+1e-6f);
  nb[tid] = v*rinv*hns[tid];
  __syncthreads();
  int m = n&7;
  float mu=meanv[n], sd=stdv[n], sc=rs[m], bi=rb[m];
  for(int col=tid; col<384; col+=256){
    float acc=0.f;
    int slot, hh;
    if(col < 96){
      for(int k=0;k<256;k++) acc = fmaf(nb[k], pw[k*96+col], acc);
      slot = 0; hh = col;
    } else {
      int cq = col-96;
      for(int k=0;k<256;k++) acc = fmaf(nb[k], qw[k*288+cq], acc);
      int qi = cq - (cq/3)*3;
      slot = 1 + qi; hh = cq/3;
    }
    float y = (acc - bi)/sc*sd + mu;
    out[(slot*1024 + n)*96 + hh] = y;
  }
}

extern "C" void kernel_launch(void* const* d_in, const int* in_sizes, int n_in,
                              void* d_out, int out_size, void* d_ws, size_t ws_size,
                              hipStream_t stream)
{
  const float* series    = (const float*)d_in[0];
  const float* rs        = (const float*)d_in[1];
  const float* rb        = (const float*)d_in[2];
  const float* up_w      = (const float*)d_in[3];
  const float* lstm_wi   = (const float*)d_in[4];
  const float* lstm_wh   = (const float*)d_in[5];
  const float* lstm_b    = (const float*)d_in[6];
  const float* norm_scale= (const float*)d_in[7];
  const float* wq        = (const float*)d_in[8];
  const float* wk        = (const float*)d_in[9];
  const float* wv        = (const float*)d_in[10];
  const float* wo        = (const float*)d_in[11];
  const float* down_w    = (const float*)d_in[12];
  const float* head_ns   = (const float*)d_in[13];
  const float* point_w   = (const float*)d_in[14];
  const float* quant_w   = (const float*)d_in[15];
  float* out = (float*)d_out;

  float* ws = (float*)d_ws;
  float*  meanv = ws;                       // 1024
  float*  stdv  = meanv + 1024;             // 1024
  float*  rmsi  = stdv  + 1024;             // 64512 (unused; layout stability)
  float*  cst   = rmsi  + 64512;            // 524288 (start reused for flag bytes)
  float*  wodf  = cst   + 524288;           // 524288
  ushort* xbuf  = (ushort*)(wodf + 524288);         // 16515072 bf16
  ushort* hsb   = xbuf  + 16515072;                 // 33030144 bf16
  ushort* qkvb  = hsb   + 33030144;                 // 49545216 bf16
  ushort* wt    = qkvb  + 49545216;                 // 6291456 bf16
  ushort* wqkvt = wt    + 6291456;                  // 1572864 bf16
  ushort* wodt  = wqkvt + 1572864;                  // 524288 bf16
  int*    bar   = (int*)cst;                        // 256 flag bytes (16 groups x 16 blocks)

  k_revin<<<1024,256,0,stream>>>(series, meanv, stdv, bar);
  k_patch<<<1024,256,0,stream>>>(series, rs, rb, up_w, meanv, stdv, xbuf);
  k_wod<<<dim3(512,4),256,0,stream>>>(wo, down_w, wodf);
  k_tr_wodt<<<dim3(8,16,4),256,0,stream>>>(wodf, wodt);
  k_tr_lstmw<<<dim3(64,24,4),256,0,stream>>>(lstm_wi, lstm_wh, wt);
  k_tr_qkvw<<<dim3(24,16,4),256,0,stream>>>(wq, wk, wv, norm_scale, wqkvt);

  for(int blk=0; blk<4; blk++){
    const ushort* wt_b = wt + blk*2048*768;
    const float*  bb   = lstm_b + blk*2048;
    k_lstm_scan<<<256,256,0,stream>>>(xbuf, hsb, wt_b, bb, (uchar*)bar, blk*NP);
    k_qkv_m<<<dim3(504,6),256,0,stream>>>(hsb, wqkvt + blk*768*512, qkvb);
    k_attn<<<dim3(4032,8),256,0,stream>>>(qkvb);
    k_bel_m<<<dim3(504,2),256,0,stream>>>(qkvb, wodt + blk*256*512, xbuf);
  }
  k_head<<<1024,256,0,stream>>>(xbuf, meanv, stdv, rs, rb, head_ns, point_w, quant_w, out);
}